// Round 14
// baseline (528.979 us; speedup 1.0000x reference)
//
#include <hip/hip_runtime.h>

#define N_NODES 100000
#define N_EDGES 1600000
#define NFEAT 128
#define NCLASS 40
#define SCAN_BLK 98   // ceil(100000 / 1024) blocks; 1024 nodes per block, 4 per thread

// ---------------- degree count (int) ----------------

__global__ void cnt_zero(int* __restrict__ cnt) {
    int i = blockIdx.x * blockDim.x + threadIdx.x;
    if (i < N_NODES) cnt[i] = 0;
}

__global__ void cnt_count(const int* __restrict__ col, int* __restrict__ cnt) {
    int e = blockIdx.x * blockDim.x + threadIdx.x;
    if (e < N_EDGES) atomicAdd(&cnt[col[e]], 1);
}

// ---------------- two-level parallel scan -> rowptr, cursor (+ dis) ----------------

// A: per-block (1024 nodes) sums
__global__ void scan_partial(const int* __restrict__ cnt, int* __restrict__ bsum) {
    __shared__ int red[256];
    int blk = blockIdx.x, tid = threadIdx.x;
    int base = blk * 1024 + tid * 4;
    int s = 0;
    if (base + 3 < N_NODES) {
        int4 v = *reinterpret_cast<const int4*>(cnt + base);
        s = v.x + v.y + v.z + v.w;
    } else {
        for (int i = 0; i < 4; ++i) if (base + i < N_NODES) s += cnt[base + i];
    }
    red[tid] = s;
    __syncthreads();
    for (int o = 128; o > 0; o >>= 1) {
        if (tid < o) red[tid] += red[tid + o];
        __syncthreads();
    }
    if (tid == 0) bsum[blk] = red[0];
}

// B: scan the 98 partials (one tiny block), write exclusive bases in place
__global__ void scan_base(int* __restrict__ bsum, int* __restrict__ rowptr) {
    __shared__ int s[128];
    int tid = threadIdx.x;  // 128 threads
    s[tid] = (tid < SCAN_BLK) ? bsum[tid] : 0;
    __syncthreads();
    for (int o = 1; o < 128; o <<= 1) {
        int v = s[tid];
        int a = (tid >= o) ? s[tid - o] : 0;
        __syncthreads();
        s[tid] = v + a;
        __syncthreads();
    }
    if (tid < SCAN_BLK) bsum[tid] = (tid == 0) ? 0 : s[tid - 1];  // exclusive base
    if (tid == 0) rowptr[N_NODES] = s[SCAN_BLK - 1];              // total (= N_EDGES)
}

// C: per-block LDS scan + coalesced rowptr/cursor/dis write
__global__ void scan_write(const int* __restrict__ cnt, const int* __restrict__ bsum,
                           int* __restrict__ rowptr, int* __restrict__ cursor,
                           float* __restrict__ dis) {
    __shared__ int psum[256];
    int blk = blockIdx.x, tid = threadIdx.x;
    int base = blk * 1024 + tid * 4;
    int c0 = 0, c1 = 0, c2 = 0, c3 = 0;
    if (base + 3 < N_NODES) {
        int4 v = *reinterpret_cast<const int4*>(cnt + base);
        c0 = v.x; c1 = v.y; c2 = v.z; c3 = v.w;
    } else {
        if (base < N_NODES)     c0 = cnt[base];
        if (base + 1 < N_NODES) c1 = cnt[base + 1];
        if (base + 2 < N_NODES) c2 = cnt[base + 2];
        if (base + 3 < N_NODES) c3 = cnt[base + 3];
    }
    int s = c0 + c1 + c2 + c3;
    psum[tid] = s;
    __syncthreads();
    for (int o = 1; o < 256; o <<= 1) {  // Hillis-Steele inclusive
        int v = psum[tid];
        int a = (tid >= o) ? psum[tid - o] : 0;
        __syncthreads();
        psum[tid] = v + a;
        __syncthreads();
    }
    int ex = psum[tid] - s + bsum[blk];  // exclusive prefix for this thread's 4 nodes
    if (base + 3 < N_NODES) {
        int4 rp = make_int4(ex, ex + c0, ex + c0 + c1, ex + c0 + c1 + c2);
        *reinterpret_cast<int4*>(rowptr + base) = rp;
        *reinterpret_cast<int4*>(cursor + base) = rp;
        float4 dv = make_float4(rsqrtf((float)c0 + 1.0f), rsqrtf((float)c1 + 1.0f),
                                rsqrtf((float)c2 + 1.0f), rsqrtf((float)c3 + 1.0f));
        *reinterpret_cast<float4*>(dis + base) = dv;
    } else {
        int r = ex;
        if (base < N_NODES)     { rowptr[base] = r;     cursor[base] = r;     dis[base] = rsqrtf((float)c0 + 1.0f);     r += c0; }
        if (base + 1 < N_NODES) { rowptr[base + 1] = r; cursor[base + 1] = r; dis[base + 1] = rsqrtf((float)c1 + 1.0f); r += c1; }
        if (base + 2 < N_NODES) { rowptr[base + 2] = r; cursor[base + 2] = r; dis[base + 2] = rsqrtf((float)c2 + 1.0f); r += c2; }
        if (base + 3 < N_NODES) { rowptr[base + 3] = r; cursor[base + 3] = r; dis[base + 3] = rsqrtf((float)c3 + 1.0f); }
    }
}

// ---------------- scatter edges into CSR: csr[slot] = src (4 B, no norm) ----------------

__global__ void scatter_csr(const int* __restrict__ row, const int* __restrict__ col,
                            int* __restrict__ cursor, int* __restrict__ csr) {
    int e = blockIdx.x * blockDim.x + threadIdx.x;
    if (e >= N_EDGES) return;
    int c = col[e];
    int slot = atomicAdd(&cursor[c], 1);
    csr[slot] = row[e];
}

// ---------------- projection: U0 = dis * (X @ W)  (N x 128 @ 128 x 40) ----------------
// thread = node; 40 accs in registers; W via wave-uniform scalar loads (constant cache)

__global__ void gemm_xw(const float* __restrict__ x, const float* __restrict__ W,
                        const float* __restrict__ dis, float* __restrict__ z) {
    int n = blockIdx.x * blockDim.x + threadIdx.x;
    if (n >= N_NODES) return;
    const float4* xr = reinterpret_cast<const float4*>(x + (size_t)n * NFEAT);
    float acc[NCLASS];
#pragma unroll
    for (int c = 0; c < NCLASS; ++c) acc[c] = 0.0f;
    for (int fb = 0; fb < NFEAT / 4; ++fb) {
        float4 xv = xr[fb];
#pragma unroll
        for (int j = 0; j < 4; ++j) {
            float xs = (&xv.x)[j];
            const float* wrow = W + (fb * 4 + j) * NCLASS;  // wave-uniform -> s_load
#pragma unroll
            for (int c = 0; c < NCLASS; ++c) acc[c] += xs * wrow[c];
        }
    }
    float d = dis[n];
    float4* zr = reinterpret_cast<float4*>(z + (size_t)n * NCLASS);
#pragma unroll
    for (int cb = 0; cb < NCLASS / 4; ++cb)
        zr[cb] = make_float4(d * acc[cb * 4], d * acc[cb * 4 + 1],
                             d * acc[cb * 4 + 2], d * acc[cb * 4 + 3]);
}

// ---------------- pull-mode hop in U-space: one wave per node, lanes 0..39 = cols ----
// U_out[c] = dis[c]^2 * (U_in[c] + sum_{r in in(c)} U_in[r])        (FINAL=0)
// out[c]   = dis[c]   * (U_in[c] + sum_{r in in(c)} U_in[r]) + b    (FINAL=1)

template <int FINAL>
__global__ void hop_pull(const int* __restrict__ rowptr, const int* __restrict__ csr,
                         const float* __restrict__ dis, const float* __restrict__ zin,
                         const float* __restrict__ b, float* __restrict__ zout) {
    int wid = (blockIdx.x * blockDim.x + threadIdx.x) >> 6;  // node
    int lane = threadIdx.x & 63;
    if (wid >= N_NODES) return;
    int beg = rowptr[wid];
    int end = rowptr[wid + 1];
    float acc = 0.0f;
    if (lane < NCLASS) acc = zin[wid * NCLASS + lane];  // self term (norm folded in scale)
    int k = beg;
    int n4 = beg + ((end - beg) & ~3);
    for (; k < n4; k += 4) {  // 4 independent gathers in flight
        int p0 = csr[k], p1 = csr[k + 1], p2 = csr[k + 2], p3 = csr[k + 3];
        if (lane < NCLASS) {
            float g0 = zin[p0 * NCLASS + lane];
            float g1 = zin[p1 * NCLASS + lane];
            float g2 = zin[p2 * NCLASS + lane];
            float g3 = zin[p3 * NCLASS + lane];
            acc += g0 + g1 + g2 + g3;
        }
    }
    for (; k < end; ++k) {
        int p = csr[k];
        if (lane < NCLASS) acc += zin[p * NCLASS + lane];
    }
    if (lane < NCLASS) {
        float d = dis[wid];
        float r;
        if (FINAL) r = d * acc + b[lane];
        else       r = d * d * acc;
        zout[wid * NCLASS + lane] = r;
    }
}

// ---------------- launch ----------------

extern "C" void kernel_launch(void* const* d_in, const int* in_sizes, int n_in,
                              void* d_out, int out_size, void* d_ws, size_t ws_size,
                              hipStream_t stream) {
    const float* x = (const float*)d_in[0];
    const int* ei = (const int*)d_in[1];   // int32 [2, E]
    const float* W = (const float*)d_in[2];
    const float* b = (const float*)d_in[3];
    // d_in[4] = k (fixed at 3 by setup)

    const int* row = ei;             // sources (x_j)
    const int* col = ei + N_EDGES;   // targets (aggregation index)

    char* ws = (char*)d_ws;
    size_t off = 0;
    auto alloc = [&](size_t bytes) { void* p = ws + off; off += (bytes + 255) & ~(size_t)255; return p; };
    int*   cnt    = (int*)  alloc((size_t)N_NODES * 4);
    float* dis    = (float*)alloc((size_t)N_NODES * 4);
    int*   rowptr = (int*)  alloc((size_t)(N_NODES + 1) * 4);
    int*   cursor = (int*)  alloc((size_t)N_NODES * 4);
    int*   bsum   = (int*)  alloc(128 * 4);
    int*   csr    = (int*)  alloc((size_t)N_EDGES * 4);            // 6.4 MB
    float* buf0   = (float*)alloc((size_t)N_NODES * NCLASS * 4);   // 16 MB
    float* outf   = (float*)d_out;

    const int B = 256;
    cnt_zero<<<(N_NODES + B - 1) / B, B, 0, stream>>>(cnt);
    cnt_count<<<(N_EDGES + B - 1) / B, B, 0, stream>>>(col, cnt);
    scan_partial<<<SCAN_BLK, 256, 0, stream>>>(cnt, bsum);
    scan_base<<<1, 128, 0, stream>>>(bsum, rowptr);
    scan_write<<<SCAN_BLK, 256, 0, stream>>>(cnt, bsum, rowptr, cursor, dis);
    scatter_csr<<<(N_EDGES + B - 1) / B, B, 0, stream>>>(row, col, cursor, csr);

    // U0 = dis * (X @ W) -> buf0  (thread per node)
    gemm_xw<<<(N_NODES + B - 1) / B, B, 0, stream>>>(x, W, dis, buf0);

    int grid_hop = (int)(((size_t)N_NODES * 64 + B - 1) / B);  // one wave per node
    // hop 1: buf0 -> out (U1)
    hop_pull<0><<<grid_hop, B, 0, stream>>>(rowptr, csr, dis, buf0, nullptr, outf);
    // hop 2: out -> buf0 (U2)
    hop_pull<0><<<grid_hop, B, 0, stream>>>(rowptr, csr, dis, outf, nullptr, buf0);
    // hop 3 (final): buf0 -> out, scale by dis and add b
    hop_pull<1><<<grid_hop, B, 0, stream>>>(rowptr, csr, dis, buf0, b, outf);
}

// Round 17
// 449.802 us; speedup vs baseline: 1.1760x; 1.1760x over previous
//
#include <hip/hip_runtime.h>

#define N_NODES 100000
#define N_EDGES 1600000
#define NFEAT 128
#define NCLASS 40
#define SCAN_BLK 98     // ceil(100000 / 1024)

#define BKT_SHIFT 9
#define BKT_COLS 512
#define N_BKT 196       // ceil(100000 / 512)
#define P1_CHUNK 4096
#define P1_GRID ((N_EDGES + P1_CHUNK - 1) / P1_CHUNK)   // 391
#define P2_CAP 12288    // bucket edge capacity (mean 8163, sigma ~90)

// ---------------- degree count (int) ----------------

__global__ void cnt_zero(int* __restrict__ cnt) {
    int i = blockIdx.x * blockDim.x + threadIdx.x;
    if (i < N_NODES) cnt[i] = 0;
}

__global__ void cnt_count(const int* __restrict__ col, int* __restrict__ cnt) {
    int e = blockIdx.x * blockDim.x + threadIdx.x;
    if (e < N_EDGES) atomicAdd(&cnt[col[e]], 1);
}

// ---------------- two-level parallel scan -> rowptr (+ dis) ----------------

__global__ void scan_partial(const int* __restrict__ cnt, int* __restrict__ bsum) {
    __shared__ int red[256];
    int blk = blockIdx.x, tid = threadIdx.x;
    int base = blk * 1024 + tid * 4;
    int s = 0;
    if (base + 3 < N_NODES) {
        int4 v = *reinterpret_cast<const int4*>(cnt + base);
        s = v.x + v.y + v.z + v.w;
    } else {
        for (int i = 0; i < 4; ++i) if (base + i < N_NODES) s += cnt[base + i];
    }
    red[tid] = s;
    __syncthreads();
    for (int o = 128; o > 0; o >>= 1) {
        if (tid < o) red[tid] += red[tid + o];
        __syncthreads();
    }
    if (tid == 0) bsum[blk] = red[0];
}

__global__ void scan_base(int* __restrict__ bsum, int* __restrict__ rowptr) {
    __shared__ int s[128];
    int tid = threadIdx.x;
    s[tid] = (tid < SCAN_BLK) ? bsum[tid] : 0;
    __syncthreads();
    for (int o = 1; o < 128; o <<= 1) {
        int v = s[tid];
        int a = (tid >= o) ? s[tid - o] : 0;
        __syncthreads();
        s[tid] = v + a;
        __syncthreads();
    }
    if (tid < SCAN_BLK) bsum[tid] = (tid == 0) ? 0 : s[tid - 1];
    if (tid == 0) rowptr[N_NODES] = s[SCAN_BLK - 1];
}

__global__ void scan_write(const int* __restrict__ cnt, const int* __restrict__ bsum,
                           int* __restrict__ rowptr, float* __restrict__ dis) {
    __shared__ int psum[256];
    int blk = blockIdx.x, tid = threadIdx.x;
    int base = blk * 1024 + tid * 4;
    int c0 = 0, c1 = 0, c2 = 0, c3 = 0;
    if (base + 3 < N_NODES) {
        int4 v = *reinterpret_cast<const int4*>(cnt + base);
        c0 = v.x; c1 = v.y; c2 = v.z; c3 = v.w;
    } else {
        if (base < N_NODES)     c0 = cnt[base];
        if (base + 1 < N_NODES) c1 = cnt[base + 1];
        if (base + 2 < N_NODES) c2 = cnt[base + 2];
        if (base + 3 < N_NODES) c3 = cnt[base + 3];
    }
    int s = c0 + c1 + c2 + c3;
    psum[tid] = s;
    __syncthreads();
    for (int o = 1; o < 256; o <<= 1) {
        int v = psum[tid];
        int a = (tid >= o) ? psum[tid - o] : 0;
        __syncthreads();
        psum[tid] = v + a;
        __syncthreads();
    }
    int ex = psum[tid] - s + bsum[blk];
    if (base + 3 < N_NODES) {
        int4 rp = make_int4(ex, ex + c0, ex + c0 + c1, ex + c0 + c1 + c2);
        *reinterpret_cast<int4*>(rowptr + base) = rp;
        float4 dv = make_float4(rsqrtf((float)c0 + 1.0f), rsqrtf((float)c1 + 1.0f),
                                rsqrtf((float)c2 + 1.0f), rsqrtf((float)c3 + 1.0f));
        *reinterpret_cast<float4*>(dis + base) = dv;
    } else {
        int r = ex;
        if (base < N_NODES)     { rowptr[base] = r;     dis[base] = rsqrtf((float)c0 + 1.0f);     r += c0; }
        if (base + 1 < N_NODES) { rowptr[base + 1] = r; dis[base + 1] = rsqrtf((float)c1 + 1.0f); r += c1; }
        if (base + 2 < N_NODES) { rowptr[base + 2] = r; dis[base + 2] = rsqrtf((float)c2 + 1.0f); r += c2; }
        if (base + 3 < N_NODES) { rowptr[base + 3] = r; dis[base + 3] = rsqrtf((float)c3 + 1.0f); }
    }
}

// ---------------- bucket cursor init: bcur[b] = rowptr[b*512] ----------------
// Pairs regions coincide with final CSR extents per bucket.

__global__ void bcur_init(const int* __restrict__ rowptr, int* __restrict__ bcur) {
    int t = threadIdx.x;
    if (t < N_BKT) bcur[t] = rowptr[t * BKT_COLS];
}

// ---------------- P1: bucket-grouped edge dump (coalesced writes) ----------------
// Block: 4096 edges -> LDS histogram over 196 buckets -> global reservation ->
// LDS regroup -> per-bucket contiguous runs written to pairs[] (int2 {src,col}).

__global__ __launch_bounds__(256) void bucket_scatter(const int* __restrict__ row,
                                                      const int* __restrict__ col,
                                                      int* __restrict__ bcur,
                                                      int2* __restrict__ pairs) {
    __shared__ int hist[256];      // bucket counts, then slot allocator
    __shared__ int pref[256];      // inclusive prefix
    __shared__ int excl[256];      // exclusive prefix snapshot
    __shared__ int gb[N_BKT];      // global base per bucket for this block
    __shared__ int2 out[P1_CHUNK];
    __shared__ int dst[P1_CHUNK];
    int tid = threadIdx.x;
    int e0 = blockIdx.x * P1_CHUNK;
    hist[tid] = 0;
    __syncthreads();
    int myr[16], myc[16];
    bool val[16];
#pragma unroll
    for (int j = 0; j < 16; ++j) {
        int e = e0 + j * 256 + tid;
        val[j] = e < N_EDGES;
        if (val[j]) {
            myc[j] = col[e];
            myr[j] = row[e];
            atomicAdd(&hist[myc[j] >> BKT_SHIFT], 1);
        }
    }
    __syncthreads();
    int v = hist[tid];
    if (tid < N_BKT && v > 0) gb[tid] = atomicAdd(&bcur[tid], v);
    else if (tid < N_BKT) gb[tid] = 0;
    pref[tid] = v;
    __syncthreads();
    for (int o = 1; o < 256; o <<= 1) {
        int vv = pref[tid];
        int a = (tid >= o) ? pref[tid - o] : 0;
        __syncthreads();
        pref[tid] = vv + a;
        __syncthreads();
    }
    excl[tid] = pref[tid] - v;
    __syncthreads();
    hist[tid] = excl[tid];  // slot allocator starts at exclusive prefix
    __syncthreads();
#pragma unroll
    for (int j = 0; j < 16; ++j) {
        if (val[j]) {
            int b = myc[j] >> BKT_SHIFT;
            int l = atomicAdd(&hist[b], 1);
            out[l] = make_int2(myr[j], myc[j]);
            dst[l] = gb[b] + (l - excl[b]);
        }
    }
    __syncthreads();
    int tot = pref[255];  // edges in this block
    for (int i = tid; i < tot; i += 256) pairs[dst[i]] = out[i];
}

// ---------------- P2: per-bucket CSR finalize (LDS scatter, coalesced out) ------

__global__ __launch_bounds__(256) void csr_build(const int* __restrict__ rowptr,
                                                 const int2* __restrict__ pairs,
                                                 int* __restrict__ csr) {
    __shared__ int cur[BKT_COLS];
    __shared__ int stage[P2_CAP];
    int b = blockIdx.x, tid = threadIdx.x;
    int lo = b * BKT_COLS;
    int hi = lo + BKT_COLS; if (hi > N_NODES) hi = N_NODES;
    int base = rowptr[lo];
    int cnt = rowptr[hi] - base;
    for (int c = tid; c < hi - lo; c += 256) cur[c] = rowptr[lo + c] - base;
    __syncthreads();
    for (int i = tid; i < cnt; i += 256) {
        int2 p = pairs[base + i];
        int s = atomicAdd(&cur[p.y - lo], 1);
        if (s < P2_CAP) stage[s] = p.x;
        else csr[base + s] = p.x;   // overflow fallback (statistically unreachable)
    }
    __syncthreads();
    int lim = cnt < P2_CAP ? cnt : P2_CAP;
    for (int i = tid; i < lim; i += 256) csr[base + i] = stage[i];
}

// ---------------- projection: U0 = dis * (X @ W) ----------------

__global__ void gemm_xw(const float* __restrict__ x, const float* __restrict__ W,
                        const float* __restrict__ dis, float* __restrict__ z) {
    int n = blockIdx.x * blockDim.x + threadIdx.x;
    if (n >= N_NODES) return;
    const float4* xr = reinterpret_cast<const float4*>(x + (size_t)n * NFEAT);
    float acc[NCLASS];
#pragma unroll
    for (int c = 0; c < NCLASS; ++c) acc[c] = 0.0f;
    for (int fb = 0; fb < NFEAT / 4; ++fb) {
        float4 xv = xr[fb];
#pragma unroll
        for (int j = 0; j < 4; ++j) {
            float xs = (&xv.x)[j];
            const float* wrow = W + (fb * 4 + j) * NCLASS;  // wave-uniform -> s_load
#pragma unroll
            for (int c = 0; c < NCLASS; ++c) acc[c] += xs * wrow[c];
        }
    }
    float d = dis[n];
    float4* zr = reinterpret_cast<float4*>(z + (size_t)n * NCLASS);
#pragma unroll
    for (int cb = 0; cb < NCLASS / 4; ++cb)
        zr[cb] = make_float4(d * acc[cb * 4], d * acc[cb * 4 + 1],
                             d * acc[cb * 4 + 2], d * acc[cb * 4 + 3]);
}

// ---------------- pull-mode hop in U-space ----------------
// U_out[c] = dis[c]^2 * (U_in[c] + sum_in U_in[r])        (FINAL=0)
// out[c]   = dis[c]   * (U_in[c] + sum_in U_in[r]) + b    (FINAL=1)

template <int FINAL>
__global__ void hop_pull(const int* __restrict__ rowptr, const int* __restrict__ csr,
                         const float* __restrict__ dis, const float* __restrict__ zin,
                         const float* __restrict__ b, float* __restrict__ zout) {
    int wid = (blockIdx.x * blockDim.x + threadIdx.x) >> 6;  // node
    int lane = threadIdx.x & 63;
    if (wid >= N_NODES) return;
    int beg = rowptr[wid];
    int end = rowptr[wid + 1];
    float acc = 0.0f;
    if (lane < NCLASS) acc = zin[wid * NCLASS + lane];
    int k = beg;
    int n4 = beg + ((end - beg) & ~3);
    for (; k < n4; k += 4) {
        int p0 = csr[k], p1 = csr[k + 1], p2 = csr[k + 2], p3 = csr[k + 3];
        if (lane < NCLASS) {
            float g0 = zin[p0 * NCLASS + lane];
            float g1 = zin[p1 * NCLASS + lane];
            float g2 = zin[p2 * NCLASS + lane];
            float g3 = zin[p3 * NCLASS + lane];
            acc += g0 + g1 + g2 + g3;
        }
    }
    for (; k < end; ++k) {
        int p = csr[k];
        if (lane < NCLASS) acc += zin[p * NCLASS + lane];
    }
    if (lane < NCLASS) {
        float d = dis[wid];
        float r;
        if (FINAL) r = d * acc + b[lane];
        else       r = d * d * acc;
        zout[wid * NCLASS + lane] = r;
    }
}

// ---------------- launch ----------------

extern "C" void kernel_launch(void* const* d_in, const int* in_sizes, int n_in,
                              void* d_out, int out_size, void* d_ws, size_t ws_size,
                              hipStream_t stream) {
    const float* x = (const float*)d_in[0];
    const int* ei = (const int*)d_in[1];   // int32 [2, E]
    const float* W = (const float*)d_in[2];
    const float* b = (const float*)d_in[3];
    // d_in[4] = k (fixed at 3 by setup)

    const int* row = ei;             // sources (x_j)
    const int* col = ei + N_EDGES;   // targets (aggregation index)

    char* ws = (char*)d_ws;
    size_t off = 0;
    auto alloc = [&](size_t bytes) { void* p = ws + off; off += (bytes + 255) & ~(size_t)255; return p; };
    int*   cnt    = (int*)  alloc((size_t)N_NODES * 4);
    float* dis    = (float*)alloc((size_t)N_NODES * 4);
    int*   rowptr = (int*)  alloc((size_t)(N_NODES + 1) * 4);
    int*   bsum   = (int*)  alloc(128 * 4);
    int*   bcur   = (int*)  alloc(256 * 4);
    int2*  pairs  = (int2*) alloc((size_t)N_EDGES * 8);            // 12.8 MB
    int*   csr    = (int*)  alloc((size_t)N_EDGES * 4);            // 6.4 MB
    float* buf0   = (float*)alloc((size_t)N_NODES * NCLASS * 4);   // 16 MB
    float* outf   = (float*)d_out;

    const int B = 256;
    cnt_zero<<<(N_NODES + B - 1) / B, B, 0, stream>>>(cnt);
    cnt_count<<<(N_EDGES + B - 1) / B, B, 0, stream>>>(col, cnt);
    scan_partial<<<SCAN_BLK, 256, 0, stream>>>(cnt, bsum);
    scan_base<<<1, 128, 0, stream>>>(bsum, rowptr);
    scan_write<<<SCAN_BLK, 256, 0, stream>>>(cnt, bsum, rowptr, dis);
    bcur_init<<<1, 256, 0, stream>>>(rowptr, bcur);
    bucket_scatter<<<P1_GRID, 256, 0, stream>>>(row, col, bcur, pairs);
    csr_build<<<N_BKT, 256, 0, stream>>>(rowptr, pairs, csr);

    // U0 = dis * (X @ W) -> buf0
    gemm_xw<<<(N_NODES + B - 1) / B, B, 0, stream>>>(x, W, dis, buf0);

    int grid_hop = (int)(((size_t)N_NODES * 64 + B - 1) / B);  // one wave per node
    hop_pull<0><<<grid_hop, B, 0, stream>>>(rowptr, csr, dis, buf0, nullptr, outf);
    hop_pull<0><<<grid_hop, B, 0, stream>>>(rowptr, csr, dis, outf, nullptr, buf0);
    hop_pull<1><<<grid_hop, B, 0, stream>>>(rowptr, csr, dis, buf0, b, outf);
}